// Round 1
// baseline (7087.791 us; speedup 1.0000x reference)
//
#include <hip/hip_runtime.h>
#include <cstdint>
#include <cstddef>

// Problem constants (fixed by the reference: B=8, S=1024, H=512, 8 speakers, 2 layers)
#define HB 8
#define SS 1024
#define HH 512
#define G3 1536  // 3*H

typedef _Float16 half8 __attribute__((ext_vector_type(8)));
typedef float f32x4 __attribute__((ext_vector_type(4)));

// ---- workspace layout (bytes) ----
static constexpr unsigned OFF_TLIST = 0;        // [8][8][1024] int : per-(sp,b) active timesteps (zero-padded)
static constexpr unsigned OFF_LEN   = 262144;   // [64] int        : chain lengths
static constexpr unsigned OFF_META  = 262400;   // [0]=maxlen
static constexpr unsigned OFF_H0    = 262656;   // 2 slots * 64 chains * 512 f32 = 262144 B
static constexpr unsigned OFF_H1    = 524800;   // same
static constexpr unsigned OFF_BAR   = 786944;   // 4 KB barrier state
static constexpr unsigned WS_NEED   = 791040;

__device__ __forceinline__ half8 cvt8(const float* p) {
  float4 u = *(const float4*)p;
  float4 v = *(const float4*)(p + 4);
  half8 h;
  h[0]=(_Float16)u.x; h[1]=(_Float16)u.y; h[2]=(_Float16)u.z; h[3]=(_Float16)u.w;
  h[4]=(_Float16)v.x; h[5]=(_Float16)v.y; h[6]=(_Float16)v.z; h[7]=(_Float16)v.w;
  return h;
}

__device__ __forceinline__ half8 zero8() {
  half8 h;
#pragma unroll
  for (int i = 0; i < 8; ++i) h[i] = (_Float16)0.f;
  return h;
}

__device__ __forceinline__ float sigm(float x) { return 1.f / (1.f + __expf(-x)); }

// ---------------- prep: build per-(sp,b) timestep lists ----------------
__global__ void prep_kernel(const int* __restrict__ spk, int* __restrict__ tlist,
                            int* __restrict__ len, int* __restrict__ meta) {
  __shared__ int slen[64];
  const int t = threadIdx.x;   // 0..63
  const int sp = t >> 3, b = t & 7;
  int cnt = 0;
  int* tl = tlist + (sp * 8 + b) * SS;
  const int4* srow = (const int4*)(spk + b * SS);
#pragma unroll 4
  for (int i = 0; i < SS / 4; ++i) {
    int4 v = srow[i];
    if (v.x == sp) tl[cnt++] = 4 * i + 0;
    if (v.y == sp) tl[cnt++] = 4 * i + 1;
    if (v.z == sp) tl[cnt++] = 4 * i + 2;
    if (v.w == sp) tl[cnt++] = 4 * i + 3;
  }
  len[t] = cnt;
  slen[t] = cnt;
  for (int i = cnt; i < SS; ++i) tl[i] = 0;  // pad so speculative reads are safe
  __syncthreads();
  if (t == 0) {
    int m = 0;
    for (int i = 0; i < 64; ++i) m = max(m, slen[i]);
    meta[0] = m;
  }
}

// ---------------- persistent GRU kernel ----------------
// 256 WGs: wg = sp*32 + og, each owns 16 outputs j0=og*16 of BOTH layers for speaker sp.
// Per round r (one device barrier each):
//   layer0 computes chain-local step r, layer1 computes step r-1 (1-round pipeline lag).
// 4 GEMMs per WG: [Wi0 x x_t], [Wh0 x h0_{r-1}], [Wi1 x h0_{r-1}], [Wh1 x h1_{r-2}]
// each M=8(batch) x N=48(3 gates x 16 outs) x K=512, K split 4-ways across waves.
__launch_bounds__(256, 1)
__global__ void gru_main(const float* __restrict__ x,
                         const float* __restrict__ Wi, const float* __restrict__ Wh,
                         const float* __restrict__ bi, const float* __restrict__ bh,
                         const int* __restrict__ tlist, const int* __restrict__ len,
                         const int* __restrict__ meta,
                         float* __restrict__ h0ring, float* __restrict__ h1ring,
                         float* __restrict__ out, unsigned* __restrict__ bar) {
  const int wg = blockIdx.x;      // 0..255
  const int sp = wg >> 5;
  const int j0 = (wg & 31) * 16;
  const int tid = threadIdx.x;
  const int w  = tid >> 6;        // wave 0..3 (owns K-quarter)
  const int l  = tid & 63;
  const int lr = l & 15;          // A-row (batch) / B-col (weight row in tile)
  const int lg = l >> 4;          // k sub-group

  __shared__ float accbuf[4][12][256];   // [wave][GEMM*3+tile][n*16+m]

  // ---- weight preload: fp32 global -> f16 register fragments (done once) ----
  const size_t WMAT = (size_t)G3 * HH;
  const float* pWi0 = Wi + (size_t)(sp * 2 + 0) * WMAT;
  const float* pWh0 = Wh + (size_t)(sp * 2 + 0) * WMAT;
  const float* pWi1 = Wi + (size_t)(sp * 2 + 1) * WMAT;
  const float* pWh1 = Wh + (size_t)(sp * 2 + 1) * WMAT;

  half8 bwi0[3][4], bwh0[3][4], bwi1[3][4], bwh1[3][4];
#pragma unroll
  for (int T = 0; T < 3; ++T) {
#pragma unroll
    for (int q = 0; q < 4; ++q) {
      const size_t row = (size_t)(T * HH + j0 + lr);   // gate T, output j0+lr
      const int k0 = lg * 8 + (w * 4 + q) * 32;
      bwi0[T][q] = cvt8(pWi0 + row * HH + k0);
      bwh0[T][q] = cvt8(pWh0 + row * HH + k0);
      bwi1[T][q] = cvt8(pWi1 + row * HH + k0);
      bwh1[T][q] = cvt8(pWh1 + row * HH + k0);
    }
  }

  // ---- gate-thread metadata: threads 0..127 = layer0 gates, 128..255 = layer1 gates ----
  const bool isA = tid < 128;
  const int u_ = isA ? tid : (tid - 128);
  const int gb = u_ >> 4;     // batch
  const int gj = u_ & 15;     // output within group
  const int Lb = len[sp * 8 + gb];
  const int* tlB = tlist + (sp * 8 + gb) * SS;
  float bAi[3], bAh[3], bBi[3], bBh[3];
#pragma unroll
  for (int g = 0; g < 3; ++g) {
    const int n = g * HH + j0 + gj;
    bAi[g] = bi[(sp * 2 + 0) * G3 + n];
    bAh[g] = bh[(sp * 2 + 0) * G3 + n];
    bBi[g] = bi[(sp * 2 + 1) * G3 + n];
    bBh[g] = bh[(sp * 2 + 1) * G3 + n];
  }

  // per-lane x-gather metadata (lanes lr<8 supply batch lr's A-row)
  const int* tlX = tlist + (sp * 8 + (lr & 7)) * SS;
  const float* xrow_base = x + (size_t)(lr & 7) * SS * HH;

  const int maxlen = meta[0];

  for (int r = 0; r <= maxlen; ++r) {
    // ---- A-operand loads (global -> f16 regs) ----
    half8 xA[4], hA0[4], hA1[4];
    {
      const int s0 = (r - 1) & 1;  // h0_{r-1}
      const int s1 = r & 1;        // h1_{r-2}
      const float* h0s = h0ring + ((size_t)(s0 * 64 + sp * 8 + (lr & 7))) * HH;
      const float* h1s = h1ring + ((size_t)(s1 * 64 + sp * 8 + (lr & 7))) * HH;
      const int tx = (lr < 8) ? tlX[r & (SS - 1)] : 0;
      const float* xs = xrow_base + (size_t)tx * HH;
#pragma unroll
      for (int q = 0; q < 4; ++q) {
        const int k0 = lg * 8 + (w * 4 + q) * 32;
        if (lr < 8) {
          xA[q]  = cvt8(xs + k0);
          hA0[q] = cvt8(h0s + k0);
          hA1[q] = cvt8(h1s + k0);
        } else {
          xA[q] = zero8(); hA0[q] = zero8(); hA1[q] = zero8();
        }
      }
    }

    // gate scalar state loads
    const bool actA = isA && (r < Lb);
    const bool actB = (!isA) && (r >= 1) && (r <= Lb);
    float hprev = 0.f;
    int tcur = 0;
    if (actA) {
      hprev = h0ring[((size_t)((((r - 1) & 1)) * 64 + sp * 8 + gb)) * HH + j0 + gj];
    } else if (actB) {
      tcur = tlB[(r - 1) & (SS - 1)];
      hprev = h1ring[((size_t)((r & 1) * 64 + sp * 8 + gb)) * HH + j0 + gj];
    }

    // ---- MFMA: 4 GEMMs x 3 gate-tiles x 4 k-steps (this wave's K-quarter) ----
    f32x4 acc[4][3];
#pragma unroll
    for (int Gm = 0; Gm < 4; ++Gm)
#pragma unroll
      for (int T = 0; T < 3; ++T)
#pragma unroll
        for (int i4 = 0; i4 < 4; ++i4) acc[Gm][T][i4] = 0.f;

#pragma unroll
    for (int T = 0; T < 3; ++T) {
#pragma unroll
      for (int q = 0; q < 4; ++q) {
        acc[0][T] = __builtin_amdgcn_mfma_f32_16x16x32_f16(xA[q],  bwi0[T][q], acc[0][T], 0, 0, 0);
        acc[1][T] = __builtin_amdgcn_mfma_f32_16x16x32_f16(hA0[q], bwh0[T][q], acc[1][T], 0, 0, 0);
        acc[2][T] = __builtin_amdgcn_mfma_f32_16x16x32_f16(hA0[q], bwi1[T][q], acc[2][T], 0, 0, 0);
        acc[3][T] = __builtin_amdgcn_mfma_f32_16x16x32_f16(hA1[q], bwh1[T][q], acc[3][T], 0, 0, 0);
      }
    }

    // ---- stage K-partials to LDS (col-major n*16+m so lane's 4 elems are contiguous) ----
#pragma unroll
    for (int Gm = 0; Gm < 4; ++Gm)
#pragma unroll
      for (int T = 0; T < 3; ++T)
        *(f32x4*)&accbuf[w][Gm * 3 + T][lr * 16 + lg * 4] = acc[Gm][T];
    __syncthreads();

    // ---- gates ----
    const int ci = gj * 16 + gb;
    if (actA) {
      float giv[3], ghv[3];
#pragma unroll
      for (int g = 0; g < 3; ++g) {
        giv[g] = accbuf[0][g][ci] + accbuf[1][g][ci] + accbuf[2][g][ci] + accbuf[3][g][ci] + bAi[g];
        ghv[g] = accbuf[0][3 + g][ci] + accbuf[1][3 + g][ci] + accbuf[2][3 + g][ci] + accbuf[3][3 + g][ci] + bAh[g];
      }
      const float rr = sigm(giv[0] + ghv[0]);
      const float zz = sigm(giv[1] + ghv[1]);
      const float nn = tanhf(giv[2] + rr * ghv[2]);
      const float hnew = (1.f - zz) * nn + zz * hprev;
      h0ring[((size_t)((r & 1) * 64 + sp * 8 + gb)) * HH + j0 + gj] = hnew;
    } else if (actB) {
      float giv[3], ghv[3];
#pragma unroll
      for (int g = 0; g < 3; ++g) {
        giv[g] = accbuf[0][6 + g][ci] + accbuf[1][6 + g][ci] + accbuf[2][6 + g][ci] + accbuf[3][6 + g][ci] + bBi[g];
        ghv[g] = accbuf[0][9 + g][ci] + accbuf[1][9 + g][ci] + accbuf[2][9 + g][ci] + accbuf[3][9 + g][ci] + bBh[g];
      }
      const float rr = sigm(giv[0] + ghv[0]);
      const float zz = sigm(giv[1] + ghv[1]);
      const float nn = tanhf(giv[2] + rr * ghv[2]);
      const float hnew = (1.f - zz) * nn + zz * hprev;
      h1ring[((size_t)(((r - 1) & 1) * 64 + sp * 8 + gb)) * HH + j0 + gj] = hnew;
      out[((size_t)(gb * SS + tcur)) * HH + j0 + gj] = hnew;
    }

    // ---- device-wide barrier (two-level, monotonic counters) ----
    __threadfence();
    __syncthreads();
    if (tid == 0) {
      const unsigned target = (unsigned)(r + 1);
      const int g8 = wg & 7;   // group by likely-XCD for cheap level-1 atomics
      unsigned a1 = __hip_atomic_fetch_add(&bar[g8 * 16], 1u, __ATOMIC_ACQ_REL, __HIP_MEMORY_SCOPE_AGENT);
      if (a1 == 32u * target - 1u) {
        unsigned a2 = __hip_atomic_fetch_add(&bar[256], 1u, __ATOMIC_ACQ_REL, __HIP_MEMORY_SCOPE_AGENT);
        if (a2 == 8u * target - 1u) {
          __hip_atomic_store(&bar[320], target, __ATOMIC_RELEASE, __HIP_MEMORY_SCOPE_AGENT);
        }
      }
      unsigned iters = 0;
      while (__hip_atomic_load(&bar[320], __ATOMIC_RELAXED, __HIP_MEMORY_SCOPE_AGENT) < target) {
        __builtin_amdgcn_s_sleep(2);
        if (++iters > 400000000u) break;   // safety against pathological hang
      }
    }
    __syncthreads();
    __threadfence();
  }
}

extern "C" void kernel_launch(void* const* d_in, const int* in_sizes, int n_in,
                              void* d_out, int out_size, void* d_ws, size_t ws_size,
                              hipStream_t stream) {
  const float* x   = (const float*)d_in[0];
  const int*   spk = (const int*)d_in[1];
  const float* Wi  = (const float*)d_in[2];
  const float* Wh  = (const float*)d_in[3];
  const float* bi  = (const float*)d_in[4];
  const float* bh  = (const float*)d_in[5];
  float* out = (float*)d_out;
  char* ws = (char*)d_ws;

  int*      tlist = (int*)(ws + OFF_TLIST);
  int*      len   = (int*)(ws + OFF_LEN);
  int*      meta  = (int*)(ws + OFF_META);
  float*    h0r   = (float*)(ws + OFF_H0);
  float*    h1r   = (float*)(ws + OFF_H1);
  unsigned* bar   = (unsigned*)(ws + OFF_BAR);

  (void)in_sizes; (void)n_in; (void)out_size; (void)ws_size;

  // zero rings + barrier state (re-done every launch; graph-capture safe)
  hipMemsetAsync(ws + OFF_H0, 0, WS_NEED - OFF_H0, stream);
  prep_kernel<<<1, 64, 0, stream>>>(spk, tlist, len, meta);
  gru_main<<<256, 256, 0, stream>>>(x, Wi, Wh, bi, bh, tlist, len, meta, h0r, h1r, out, bar);
}

// Round 2
// 1231.204 us; speedup vs baseline: 5.7568x; 5.7568x over previous
//
#include <hip/hip_runtime.h>
#include <cstdint>
#include <cstddef>

// Problem constants (fixed by the reference: B=8, S=1024, H=512, 8 speakers, 2 layers)
#define HB 8
#define SS 1024
#define HH 512
#define G3 1536  // 3*H

typedef _Float16 half8 __attribute__((ext_vector_type(8)));
typedef float f32x4 __attribute__((ext_vector_type(4)));

// ---- workspace layout (bytes) ----
static constexpr unsigned OFF_TLIST = 0;        // [8][8][1024] int : per-(sp,b) active timesteps (zero-padded)
static constexpr unsigned OFF_LEN   = 262144;   // [64] int        : chain lengths
static constexpr unsigned OFF_META  = 262400;   // [8] int         : per-speaker max chain length
static constexpr unsigned OFF_H0    = 262656;   // 2 slots * 64 chains * 512 f32 = 262144 B
static constexpr unsigned OFF_H1    = 524800;   // same
static constexpr unsigned OFF_BAR   = 786944;   // 4 KB barrier state (bar[sp*32])
static constexpr unsigned WS_NEED   = 791040;

__device__ __forceinline__ half8 cvt8(const float* p) {
  float4 u = *(const float4*)p;
  float4 v = *(const float4*)(p + 4);
  half8 h;
  h[0]=(_Float16)u.x; h[1]=(_Float16)u.y; h[2]=(_Float16)u.z; h[3]=(_Float16)u.w;
  h[4]=(_Float16)v.x; h[5]=(_Float16)v.y; h[6]=(_Float16)v.z; h[7]=(_Float16)v.w;
  return h;
}

// device-coherent (sc0 sc1, bypasses L1+L2) 8-float load, as 4x 64-bit relaxed atomics
__device__ __forceinline__ half8 cvt8_cg(const float* p) {
  const unsigned long long* q = (const unsigned long long*)p;
  half8 h;
#pragma unroll
  for (int i = 0; i < 4; ++i) {
    unsigned long long u = __hip_atomic_load(q + i, __ATOMIC_RELAXED, __HIP_MEMORY_SCOPE_AGENT);
    union { unsigned u32; float f; } lo, hi;
    lo.u32 = (unsigned)u; hi.u32 = (unsigned)(u >> 32);
    h[2*i]   = (_Float16)lo.f;
    h[2*i+1] = (_Float16)hi.f;
  }
  return h;
}

__device__ __forceinline__ half8 zero8() {
  half8 h;
#pragma unroll
  for (int i = 0; i < 8; ++i) h[i] = (_Float16)0.f;
  return h;
}

__device__ __forceinline__ float sigm(float x) { return 1.f / (1.f + __expf(-x)); }

// ---------------- prep: build per-(sp,b) timestep lists ----------------
__global__ void prep_kernel(const int* __restrict__ spk, int* __restrict__ tlist,
                            int* __restrict__ len, int* __restrict__ meta) {
  __shared__ int slen[64];
  const int t = threadIdx.x;   // 0..63
  const int sp = t >> 3, b = t & 7;
  int cnt = 0;
  int* tl = tlist + (sp * 8 + b) * SS;
  const int4* srow = (const int4*)(spk + b * SS);
#pragma unroll 4
  for (int i = 0; i < SS / 4; ++i) {
    int4 v = srow[i];
    if (v.x == sp) tl[cnt++] = 4 * i + 0;
    if (v.y == sp) tl[cnt++] = 4 * i + 1;
    if (v.z == sp) tl[cnt++] = 4 * i + 2;
    if (v.w == sp) tl[cnt++] = 4 * i + 3;
  }
  len[t] = cnt;
  slen[t] = cnt;
  for (int i = cnt; i < SS; ++i) tl[i] = 0;  // pad so speculative reads are safe
  __syncthreads();
  if (t < 8) {
    int m = 0;
    for (int i = 0; i < 8; ++i) m = max(m, slen[t * 8 + i]);
    meta[t] = m;
  }
}

// ---------------- persistent GRU kernel ----------------
// 256 WGs: wg = sp*32 + og, each owns 16 outputs j0=og*16 of BOTH layers for speaker sp.
// Per round r (one per-speaker barrier each):
//   layer0 computes chain-local step r, layer1 computes step r-1 (1-round pipeline lag).
// 4 GEMMs per WG: [Wi0 x x_t], [Wh0 x h0_{r-1}], [Wi1 x h0_{r-1}], [Wh1 x h1_{r-2}]
// each M=8(batch) x N=48(3 gates x 16 outs) x K=512, K split 4-ways across waves.
// Cross-WG data (h rings) uses RELAXED/AGENT atomics (sc0 sc1 -> device-coherent,
// bypass L1/L2) so NO fences are needed; __syncthreads' vmcnt(0) before the
// barrier-arrive atomic provides release ordering.
__launch_bounds__(256, 1)
__global__ void gru_main(const float* __restrict__ x,
                         const float* __restrict__ Wi, const float* __restrict__ Wh,
                         const float* __restrict__ bi, const float* __restrict__ bh,
                         const int* __restrict__ tlist, const int* __restrict__ len,
                         const int* __restrict__ meta,
                         float* __restrict__ h0ring, float* __restrict__ h1ring,
                         float* __restrict__ out, unsigned* __restrict__ bar) {
  const int wg = blockIdx.x;      // 0..255
  const int sp = wg >> 5;
  const int j0 = (wg & 31) * 16;
  const int tid = threadIdx.x;
  const int w  = tid >> 6;        // wave 0..3 (owns K-quarter)
  const int l  = tid & 63;
  const int lr = l & 15;          // A-row (batch) / B-col (weight row in tile)
  const int lg = l >> 4;          // k sub-group

  // [wave][GEMM*3+gate][m*17+n]  (pad 17 -> <=4-way write conflicts, conflict-free gate reads)
  __shared__ float accbuf[4][12][272];

  // ---- weight preload: fp32 global -> f16 register fragments (done once) ----
  const size_t WMAT = (size_t)G3 * HH;
  const float* pWi0 = Wi + (size_t)(sp * 2 + 0) * WMAT;
  const float* pWh0 = Wh + (size_t)(sp * 2 + 0) * WMAT;
  const float* pWi1 = Wi + (size_t)(sp * 2 + 1) * WMAT;
  const float* pWh1 = Wh + (size_t)(sp * 2 + 1) * WMAT;

  half8 bwi0[3][4], bwh0[3][4], bwi1[3][4], bwh1[3][4];
#pragma unroll
  for (int T = 0; T < 3; ++T) {
#pragma unroll
    for (int q = 0; q < 4; ++q) {
      const size_t row = (size_t)(T * HH + j0 + lr);   // gate T, output j0+lr
      const int k0 = lg * 8 + (w * 4 + q) * 32;
      bwi0[T][q] = cvt8(pWi0 + row * HH + k0);
      bwh0[T][q] = cvt8(pWh0 + row * HH + k0);
      bwi1[T][q] = cvt8(pWi1 + row * HH + k0);
      bwh1[T][q] = cvt8(pWh1 + row * HH + k0);
    }
  }

  // ---- gate-thread metadata: threads 0..127 = layer0 gates, 128..255 = layer1 gates ----
  const bool isA = tid < 128;
  const int u_ = isA ? tid : (tid - 128);
  const int gb = u_ >> 4;     // batch
  const int gj = u_ & 15;     // output within group
  const int Lb = len[sp * 8 + gb];
  const int* tlB = tlist + (sp * 8 + gb) * SS;
  float bAi[3], bAh[3], bBi[3], bBh[3];
#pragma unroll
  for (int g = 0; g < 3; ++g) {
    const int n = g * HH + j0 + gj;
    bAi[g] = bi[(sp * 2 + 0) * G3 + n];
    bAh[g] = bh[(sp * 2 + 0) * G3 + n];
    bBi[g] = bi[(sp * 2 + 1) * G3 + n];
    bBh[g] = bh[(sp * 2 + 1) * G3 + n];
  }

  // per-lane x-gather metadata (lanes lr<8 supply batch lr's A-row)
  const int* tlX = tlist + (sp * 8 + (lr & 7)) * SS;
  const float* xrow_base = x + (size_t)(lr & 7) * SS * HH;

  const int maxlen = meta[sp];
  unsigned* barsp = bar + sp * 32;

  for (int r = 0; r <= maxlen; ++r) {
    // ---- A-operand loads ----
    // x: plain cached loads. h rings: device-coherent atomic loads.
    half8 xA[4], hA0[4], hA1[4];
    {
      const int s0 = (r - 1) & 1;  // h0_{r-1}
      const int s1 = r & 1;        // h1_{r-2}
      const float* h0s = h0ring + ((size_t)(s0 * 64 + sp * 8 + (lr & 7))) * HH;
      const float* h1s = h1ring + ((size_t)(s1 * 64 + sp * 8 + (lr & 7))) * HH;
      const int tx = (lr < 8) ? tlX[r & (SS - 1)] : 0;
      const float* xs = xrow_base + (size_t)tx * HH;
#pragma unroll
      for (int q = 0; q < 4; ++q) {
        const int k0 = lg * 8 + (w * 4 + q) * 32;
        if (lr < 8) {
          xA[q]  = cvt8(xs + k0);
          hA0[q] = cvt8_cg(h0s + k0);
          hA1[q] = cvt8_cg(h1s + k0);
        } else {
          xA[q] = zero8(); hA0[q] = zero8(); hA1[q] = zero8();
        }
      }
    }

    // gate scalar state loads (device-coherent)
    const bool actA = isA && (r < Lb);
    const bool actB = (!isA) && (r >= 1) && (r <= Lb);
    float hprev = 0.f;
    int tcur = 0;
    if (actA) {
      hprev = __hip_atomic_load(
          &h0ring[((size_t)((((r - 1) & 1)) * 64 + sp * 8 + gb)) * HH + j0 + gj],
          __ATOMIC_RELAXED, __HIP_MEMORY_SCOPE_AGENT);
    } else if (actB) {
      tcur = tlB[(r - 1) & (SS - 1)];
      hprev = __hip_atomic_load(
          &h1ring[((size_t)((r & 1) * 64 + sp * 8 + gb)) * HH + j0 + gj],
          __ATOMIC_RELAXED, __HIP_MEMORY_SCOPE_AGENT);
    }

    // ---- MFMA: 4 GEMMs x 3 gate-tiles x 4 k-steps (this wave's K-quarter) ----
    f32x4 acc[4][3];
#pragma unroll
    for (int Gm = 0; Gm < 4; ++Gm)
#pragma unroll
      for (int T = 0; T < 3; ++T)
#pragma unroll
        for (int i4 = 0; i4 < 4; ++i4) acc[Gm][T][i4] = 0.f;

#pragma unroll
    for (int T = 0; T < 3; ++T) {
#pragma unroll
      for (int q = 0; q < 4; ++q) {
        acc[0][T] = __builtin_amdgcn_mfma_f32_16x16x32_f16(xA[q],  bwi0[T][q], acc[0][T], 0, 0, 0);
        acc[1][T] = __builtin_amdgcn_mfma_f32_16x16x32_f16(hA0[q], bwh0[T][q], acc[1][T], 0, 0, 0);
        acc[2][T] = __builtin_amdgcn_mfma_f32_16x16x32_f16(hA0[q], bwi1[T][q], acc[2][T], 0, 0, 0);
        acc[3][T] = __builtin_amdgcn_mfma_f32_16x16x32_f16(hA1[q], bwh1[T][q], acc[3][T], 0, 0, 0);
      }
    }

    // ---- stage K-partials to LDS at [m*17+n] (C elem: m = lg*4+e (batch), n = lr (output)) ----
#pragma unroll
    for (int Gm = 0; Gm < 4; ++Gm)
#pragma unroll
      for (int T = 0; T < 3; ++T)
#pragma unroll
        for (int e = 0; e < 4; ++e)
          accbuf[w][Gm * 3 + T][(lg * 4 + e) * 17 + lr] = acc[Gm][T][e];
    __syncthreads();

    // ---- gates ----
    const int ci = gb * 17 + gj;
    if (actA) {
      float giv[3], ghv[3];
#pragma unroll
      for (int g = 0; g < 3; ++g) {
        giv[g] = accbuf[0][g][ci] + accbuf[1][g][ci] + accbuf[2][g][ci] + accbuf[3][g][ci] + bAi[g];
        ghv[g] = accbuf[0][3 + g][ci] + accbuf[1][3 + g][ci] + accbuf[2][3 + g][ci] + accbuf[3][3 + g][ci] + bAh[g];
      }
      const float rr = sigm(giv[0] + ghv[0]);
      const float zz = sigm(giv[1] + ghv[1]);
      const float nn = tanhf(giv[2] + rr * ghv[2]);
      const float hnew = (1.f - zz) * nn + zz * hprev;
      __hip_atomic_store(&h0ring[((size_t)((r & 1) * 64 + sp * 8 + gb)) * HH + j0 + gj],
                         hnew, __ATOMIC_RELAXED, __HIP_MEMORY_SCOPE_AGENT);
    } else if (actB) {
      float giv[3], ghv[3];
#pragma unroll
      for (int g = 0; g < 3; ++g) {
        giv[g] = accbuf[0][6 + g][ci] + accbuf[1][6 + g][ci] + accbuf[2][6 + g][ci] + accbuf[3][6 + g][ci] + bBi[g];
        ghv[g] = accbuf[0][9 + g][ci] + accbuf[1][9 + g][ci] + accbuf[2][9 + g][ci] + accbuf[3][9 + g][ci] + bBh[g];
      }
      const float rr = sigm(giv[0] + ghv[0]);
      const float zz = sigm(giv[1] + ghv[1]);
      const float nn = tanhf(giv[2] + rr * ghv[2]);
      const float hnew = (1.f - zz) * nn + zz * hprev;
      __hip_atomic_store(&h1ring[((size_t)(((r - 1) & 1) * 64 + sp * 8 + gb)) * HH + j0 + gj],
                         hnew, __ATOMIC_RELAXED, __HIP_MEMORY_SCOPE_AGENT);
      out[((size_t)(gb * SS + tcur)) * HH + j0 + gj] = hnew;
    }

    // ---- per-speaker barrier (32 WGs), fully relaxed: __syncthreads supplies vmcnt(0)
    //      release before the arrive; coherent ring accesses need no cache maintenance ----
    __syncthreads();
    if (tid == 0) {
      const unsigned target = 32u * (unsigned)(r + 1);
      __hip_atomic_fetch_add(barsp, 1u, __ATOMIC_RELAXED, __HIP_MEMORY_SCOPE_AGENT);
      unsigned iters = 0;
      while (__hip_atomic_load(barsp, __ATOMIC_RELAXED, __HIP_MEMORY_SCOPE_AGENT) < target) {
        __builtin_amdgcn_s_sleep(1);
        if (++iters > 400000000u) break;   // safety against pathological hang
      }
    }
    __syncthreads();
  }
}

extern "C" void kernel_launch(void* const* d_in, const int* in_sizes, int n_in,
                              void* d_out, int out_size, void* d_ws, size_t ws_size,
                              hipStream_t stream) {
  const float* x   = (const float*)d_in[0];
  const int*   spk = (const int*)d_in[1];
  const float* Wi  = (const float*)d_in[2];
  const float* Wh  = (const float*)d_in[3];
  const float* bi  = (const float*)d_in[4];
  const float* bh  = (const float*)d_in[5];
  float* out = (float*)d_out;
  char* ws = (char*)d_ws;

  int*      tlist = (int*)(ws + OFF_TLIST);
  int*      len   = (int*)(ws + OFF_LEN);
  int*      meta  = (int*)(ws + OFF_META);
  float*    h0r   = (float*)(ws + OFF_H0);
  float*    h1r   = (float*)(ws + OFF_H1);
  unsigned* bar   = (unsigned*)(ws + OFF_BAR);

  (void)in_sizes; (void)n_in; (void)out_size; (void)ws_size;

  // zero rings + barrier state (re-done every launch; graph-capture safe)
  hipMemsetAsync(ws + OFF_H0, 0, WS_NEED - OFF_H0, stream);
  prep_kernel<<<1, 64, 0, stream>>>(spk, tlist, len, meta);
  gru_main<<<256, 256, 0, stream>>>(x, Wi, Wh, bi, bh, tlist, len, meta, h0r, h1r, out, bar);
}

// Round 3
// 661.512 us; speedup vs baseline: 10.7145x; 1.8612x over previous
//
#include <hip/hip_runtime.h>
#include <cstdint>
#include <cstddef>

// Problem constants (fixed by the reference: B=8, S=1024, H=512, 8 speakers, 2 layers)
#define SS 1024
#define HH 512
#define G3 1536  // 3*H

typedef _Float16 half8 __attribute__((ext_vector_type(8)));
typedef float f32x4 __attribute__((ext_vector_type(4)));

// ---- workspace layout (bytes) ----
static constexpr unsigned OFF_TLIST = 0;               // [8][8][1024] int
static constexpr unsigned OFF_LEN   = 262144;          // [64] int
static constexpr unsigned OFF_META  = 262400;          // [8] int per-speaker max chain len
static constexpr unsigned OFF_H0    = 262656;          // ushort[2][64][512] = 131072 B
static constexpr unsigned OFF_H1    = OFF_H0 + 131072; // ushort[2][64][512]
static constexpr unsigned OFF_BAR   = OFF_H1 + 131072; // u32 flags[8][32] (+pad)
static constexpr unsigned WS_NEED   = OFF_BAR + 4096;

__device__ __forceinline__ half8 cvt8(const float* p) {
  float4 u = *(const float4*)p;
  float4 v = *(const float4*)(p + 4);
  half8 h;
  h[0]=(_Float16)u.x; h[1]=(_Float16)u.y; h[2]=(_Float16)u.z; h[3]=(_Float16)u.w;
  h[4]=(_Float16)v.x; h[5]=(_Float16)v.y; h[6]=(_Float16)v.z; h[7]=(_Float16)v.w;
  return h;
}

__device__ __forceinline__ float sigm(float x) { return 1.f / (1.f + __expf(-x)); }

// ---------------- prep: build per-(sp,b) timestep lists ----------------
__global__ void prep_kernel(const int* __restrict__ spk, int* __restrict__ tlist,
                            int* __restrict__ len, int* __restrict__ meta) {
  __shared__ int slen[64];
  const int t = threadIdx.x;   // 0..63
  const int sp = t >> 3, b = t & 7;
  int cnt = 0;
  int* tl = tlist + (sp * 8 + b) * SS;
  const int4* srow = (const int4*)(spk + b * SS);
#pragma unroll 4
  for (int i = 0; i < SS / 4; ++i) {
    int4 v = srow[i];
    if (v.x == sp) tl[cnt++] = 4 * i + 0;
    if (v.y == sp) tl[cnt++] = 4 * i + 1;
    if (v.z == sp) tl[cnt++] = 4 * i + 2;
    if (v.w == sp) tl[cnt++] = 4 * i + 3;
  }
  len[t] = cnt;
  slen[t] = cnt;
  for (int i = cnt; i < SS; ++i) tl[i] = 0;  // pad so speculative reads are safe
  __syncthreads();
  if (t < 8) {
    int m = 0;
    for (int i = 0; i < 8; ++i) m = max(m, slen[t * 8 + i]);
    meta[t] = m;
  }
}

// ---------------- persistent GRU kernel ----------------
// 256 WGs: wg -> sp = wg&7 (XCD-grouped), og = wg>>3; WG owns outputs j0=og*16 of
// BOTH layers for speaker sp. One per-speaker flag barrier per round.
// Rings are f16 (the MFMA A operand is f16 anyway; hprev stays f32 in registers).
// Transport: ring -> LDS via coalesced 64-bit agent-scope loads (dense, all threads),
// then ds_read_b128 A-fragments. x-GEMM (Wi0*x_{r+1}) precomputed during the poll.
__launch_bounds__(256, 1)
__global__ void gru_main(const float* __restrict__ x,
                         const float* __restrict__ Wi, const float* __restrict__ Wh,
                         const float* __restrict__ bi, const float* __restrict__ bh,
                         const int* __restrict__ tlist, const int* __restrict__ len,
                         const int* __restrict__ meta,
                         unsigned short* __restrict__ h0ring,
                         unsigned short* __restrict__ h1ring,
                         float* __restrict__ out, unsigned* __restrict__ bar) {
  const int wg = blockIdx.x;      // 0..255
  const int sp = wg & 7;          // speaker grouped by XCD (blockIdx % 8)
  const int og = wg >> 3;         // 0..31
  const int j0 = og * 16;
  const int tid = threadIdx.x;
  const int w  = tid >> 6;        // wave 0..3 (owns K-quarter)
  const int l  = tid & 63;
  const int lr = l & 15;          // A-row (batch) / B-col (weight row in tile)
  const int lg = l >> 4;          // k sub-group
  const int b8 = lr & 7;          // batch row (rows 8-15 duplicate 0-7; C rows 8-15 unread)

  __shared__ float accbuf[4][12][272];      // [wave][GEMM*3+gate][m*17+n]
  __shared__ _Float16 hstage[2][8][536];    // [ring][batch][512 f16 + 24 pad] stride 1072B

  // ---- weight preload: fp32 global -> f16 register fragments (done once) ----
  const size_t WMAT = (size_t)G3 * HH;
  const float* pWi0 = Wi + (size_t)(sp * 2 + 0) * WMAT;
  const float* pWh0 = Wh + (size_t)(sp * 2 + 0) * WMAT;
  const float* pWi1 = Wi + (size_t)(sp * 2 + 1) * WMAT;
  const float* pWh1 = Wh + (size_t)(sp * 2 + 1) * WMAT;

  half8 bwi0[3][4], bwh0[3][4], bwi1[3][4], bwh1[3][4];
#pragma unroll
  for (int T = 0; T < 3; ++T) {
#pragma unroll
    for (int q = 0; q < 4; ++q) {
      const size_t row = (size_t)(T * HH + j0 + lr);
      const int k0 = lg * 8 + (w * 4 + q) * 32;
      bwi0[T][q] = cvt8(pWi0 + row * HH + k0);
      bwh0[T][q] = cvt8(pWh0 + row * HH + k0);
      bwi1[T][q] = cvt8(pWi1 + row * HH + k0);
      bwh1[T][q] = cvt8(pWh1 + row * HH + k0);
    }
  }

  // ---- gate-thread metadata: threads 0..127 = layer0, 128..255 = layer1 ----
  const bool isA = tid < 128;
  const int u_ = isA ? tid : (tid - 128);
  const int gb = u_ >> 4;     // batch
  const int gj = u_ & 15;     // output within group
  const int Lb = len[sp * 8 + gb];
  const int* tlB = tlist + (sp * 8 + gb) * SS;
  float bAi[3], bAh[3], bBi[3], bBh[3];
#pragma unroll
  for (int g = 0; g < 3; ++g) {
    const int n = g * HH + j0 + gj;
    bAi[g] = bi[(sp * 2 + 0) * G3 + n];
    bAh[g] = bh[(sp * 2 + 0) * G3 + n];
    bBi[g] = bi[(sp * 2 + 1) * G3 + n];
    bBh[g] = bh[(sp * 2 + 1) * G3 + n];
  }

  // per-lane x-gather metadata (A row b8 supplies batch b8)
  const int* tlX = tlist + (sp * 8 + b8) * SS;
  const float* xrow_base = x + (size_t)b8 * SS * HH;

  const int maxlen = meta[sp];
  unsigned* flg = bar + sp * 32;

  float h0prev = 0.f, h1prev = 0.f;   // recurrent state for this thread's (gb, j0+gj)

  // ---- prologue: GEMM0 (Wi0 * x_0) into accbuf[w][0..2] ----
  {
    const int tx = tlX[0];
    const float* xs = xrow_base + (size_t)tx * HH;
    half8 xf[4];
    f32x4 a0[3];
#pragma unroll
    for (int T = 0; T < 3; ++T)
#pragma unroll
      for (int e = 0; e < 4; ++e) a0[T][e] = 0.f;
#pragma unroll
    for (int q = 0; q < 4; ++q) xf[q] = cvt8(xs + lg * 8 + (w * 4 + q) * 32);
#pragma unroll
    for (int T = 0; T < 3; ++T)
#pragma unroll
      for (int q = 0; q < 4; ++q)
        a0[T] = __builtin_amdgcn_mfma_f32_16x16x32_f16(xf[q], bwi0[T][q], a0[T], 0, 0, 0);
#pragma unroll
    for (int T = 0; T < 3; ++T)
#pragma unroll
      for (int e = 0; e < 4; ++e)
        accbuf[w][T][(lg * 4 + e) * 17 + lr] = a0[T][e];
  }

  for (int r = 0; r <= maxlen; ++r) {
    // ---- stage rings -> LDS: coalesced 64-bit agent-scope loads, all 256 threads ----
    {
      const int s0 = (r - 1) & 1;  // h0_{r-1}
      const int s1 = r & 1;        // h1_{r-2}
      const unsigned long long* src0 =
          (const unsigned long long*)(h0ring + ((size_t)(s0 * 64 + sp * 8)) * HH);
      const unsigned long long* src1 =
          (const unsigned long long*)(h1ring + ((size_t)(s1 * 64 + sp * 8)) * HH);
      unsigned long long v0[4], v1[4];
#pragma unroll
      for (int i = 0; i < 4; ++i) {
        const int e = i * 256 + tid;       // u64 index within 8KB slice
        v0[i] = __hip_atomic_load(src0 + e, __ATOMIC_RELAXED, __HIP_MEMORY_SCOPE_AGENT);
        v1[i] = __hip_atomic_load(src1 + e, __ATOMIC_RELAXED, __HIP_MEMORY_SCOPE_AGENT);
      }
#pragma unroll
      for (int i = 0; i < 4; ++i) {
        const int e = i * 256 + tid;
        const int row = e >> 7;            // 128 u64 per batch row
        const int col = e & 127;
        *(unsigned long long*)((char*)&hstage[0][row][0] + col * 8) = v0[i];
        *(unsigned long long*)((char*)&hstage[1][row][0] + col * 8) = v1[i];
      }
    }
    __syncthreads();

    // ---- A-frags from LDS + 36 MFMA (Wh0*h0, Wi1*h0, Wh1*h1) ----
    half8 hA0[4], hA1[4];
#pragma unroll
    for (int q = 0; q < 4; ++q) {
      const int k0 = lg * 8 + (w * 4 + q) * 32;
      hA0[q] = *(const half8*)((const char*)&hstage[0][b8][0] + k0 * 2);
      hA1[q] = *(const half8*)((const char*)&hstage[1][b8][0] + k0 * 2);
    }
    f32x4 acc[3][3];
#pragma unroll
    for (int Gm = 0; Gm < 3; ++Gm)
#pragma unroll
      for (int T = 0; T < 3; ++T)
#pragma unroll
        for (int e = 0; e < 4; ++e) acc[Gm][T][e] = 0.f;
#pragma unroll
    for (int T = 0; T < 3; ++T) {
#pragma unroll
      for (int q = 0; q < 4; ++q) {
        acc[0][T] = __builtin_amdgcn_mfma_f32_16x16x32_f16(hA0[q], bwh0[T][q], acc[0][T], 0, 0, 0);
        acc[1][T] = __builtin_amdgcn_mfma_f32_16x16x32_f16(hA0[q], bwi1[T][q], acc[1][T], 0, 0, 0);
        acc[2][T] = __builtin_amdgcn_mfma_f32_16x16x32_f16(hA1[q], bwh1[T][q], acc[2][T], 0, 0, 0);
      }
    }
#pragma unroll
    for (int Gm = 0; Gm < 3; ++Gm)
#pragma unroll
      for (int T = 0; T < 3; ++T)
#pragma unroll
        for (int e = 0; e < 4; ++e)
          accbuf[w][3 + Gm * 3 + T][(lg * 4 + e) * 17 + lr] = acc[Gm][T][e];
    __syncthreads();

    // ---- gates (hprev lives in registers; ring stores are f16) ----
    const bool actA = isA && (r < Lb);
    const bool actB = (!isA) && (r >= 1) && (r <= Lb);
    const int ci = gb * 17 + gj;
    if (actA) {
      float giv[3], ghv[3];
#pragma unroll
      for (int g = 0; g < 3; ++g) {
        giv[g] = accbuf[0][g][ci] + accbuf[1][g][ci] + accbuf[2][g][ci] + accbuf[3][g][ci] + bAi[g];
        ghv[g] = accbuf[0][3 + g][ci] + accbuf[1][3 + g][ci] + accbuf[2][3 + g][ci] + accbuf[3][3 + g][ci] + bAh[g];
      }
      const float rr = sigm(giv[0] + ghv[0]);
      const float zz = sigm(giv[1] + ghv[1]);
      const float nn = tanhf(giv[2] + rr * ghv[2]);
      const float hnew = (1.f - zz) * nn + zz * h0prev;
      h0prev = hnew;
      union { _Float16 h; unsigned short u; } cv; cv.h = (_Float16)hnew;
      __hip_atomic_store(&h0ring[((size_t)((r & 1) * 64 + sp * 8 + gb)) * HH + j0 + gj],
                         cv.u, __ATOMIC_RELAXED, __HIP_MEMORY_SCOPE_AGENT);
    } else if (actB) {
      float giv[3], ghv[3];
#pragma unroll
      for (int g = 0; g < 3; ++g) {
        giv[g] = accbuf[0][6 + g][ci] + accbuf[1][6 + g][ci] + accbuf[2][6 + g][ci] + accbuf[3][6 + g][ci] + bBi[g];
        ghv[g] = accbuf[0][9 + g][ci] + accbuf[1][9 + g][ci] + accbuf[2][9 + g][ci] + accbuf[3][9 + g][ci] + bBh[g];
      }
      const float rr = sigm(giv[0] + ghv[0]);
      const float zz = sigm(giv[1] + ghv[1]);
      const float nn = tanhf(giv[2] + rr * ghv[2]);
      const float hnew = (1.f - zz) * nn + zz * h1prev;
      h1prev = hnew;
      const int tcur = tlB[(r - 1) & (SS - 1)];
      union { _Float16 h; unsigned short u; } cv; cv.h = (_Float16)hnew;
      __hip_atomic_store(&h1ring[((size_t)(((r - 1) & 1) * 64 + sp * 8 + gb)) * HH + j0 + gj],
                         cv.u, __ATOMIC_RELAXED, __HIP_MEMORY_SCOPE_AGENT);
      out[((size_t)(gb * SS + tcur)) * HH + j0 + gj] = hnew;
    }

    // ---- barrier: drain stores, publish flag, precompute x-GEMM for r+1, poll ----
    __syncthreads();   // waits vmcnt(0): all ring stores of this WG are globally visible
    if (tid == 0)
      __hip_atomic_store(&flg[og], (unsigned)(r + 1), __ATOMIC_RELAXED, __HIP_MEMORY_SCOPE_AGENT);

    {  // GEMM0 = Wi0 * x_{r+1}, overlaps the poll below (h-independent)
      const int tx = tlX[(r + 1) & (SS - 1)];
      const float* xs = xrow_base + (size_t)tx * HH;
      half8 xf[4];
      f32x4 a0[3];
#pragma unroll
      for (int T = 0; T < 3; ++T)
#pragma unroll
        for (int e = 0; e < 4; ++e) a0[T][e] = 0.f;
#pragma unroll
      for (int q = 0; q < 4; ++q) xf[q] = cvt8(xs + lg * 8 + (w * 4 + q) * 32);
#pragma unroll
      for (int T = 0; T < 3; ++T)
#pragma unroll
        for (int q = 0; q < 4; ++q)
          a0[T] = __builtin_amdgcn_mfma_f32_16x16x32_f16(xf[q], bwi0[T][q], a0[T], 0, 0, 0);
#pragma unroll
      for (int T = 0; T < 3; ++T)
#pragma unroll
        for (int e = 0; e < 4; ++e)
          accbuf[w][T][(lg * 4 + e) * 17 + lr] = a0[T][e];
    }

    if (tid < 64) {  // wave 0 polls the 32 flags (lanes duplicate over 32 slots)
      const unsigned tgt = (unsigned)(r + 1);
      const unsigned* f = flg + (tid & 31);
      unsigned iters = 0;
      while (__hip_atomic_load(f, __ATOMIC_RELAXED, __HIP_MEMORY_SCOPE_AGENT) < tgt) {
        __builtin_amdgcn_s_sleep(1);
        if (++iters > 100000000u) break;   // safety
      }
    }
    asm volatile("" ::: "memory");
    __syncthreads();
  }
}

extern "C" void kernel_launch(void* const* d_in, const int* in_sizes, int n_in,
                              void* d_out, int out_size, void* d_ws, size_t ws_size,
                              hipStream_t stream) {
  const float* x   = (const float*)d_in[0];
  const int*   spk = (const int*)d_in[1];
  const float* Wi  = (const float*)d_in[2];
  const float* Wh  = (const float*)d_in[3];
  const float* bi  = (const float*)d_in[4];
  const float* bh  = (const float*)d_in[5];
  float* out = (float*)d_out;
  char* ws = (char*)d_ws;

  int*            tlist = (int*)(ws + OFF_TLIST);
  int*            len   = (int*)(ws + OFF_LEN);
  int*            meta  = (int*)(ws + OFF_META);
  unsigned short* h0r   = (unsigned short*)(ws + OFF_H0);
  unsigned short* h1r   = (unsigned short*)(ws + OFF_H1);
  unsigned*       bar   = (unsigned*)(ws + OFF_BAR);

  (void)in_sizes; (void)n_in; (void)out_size; (void)ws_size;

  // zero rings + barrier flags (re-done every launch; graph-capture safe)
  hipMemsetAsync(ws + OFF_H0, 0, WS_NEED - OFF_H0, stream);
  prep_kernel<<<1, 64, 0, stream>>>(spk, tlist, len, meta);
  gru_main<<<256, 256, 0, stream>>>(x, Wi, Wh, bi, bh, tlist, len, meta, h0r, h1r, out, bar);
}